// Round 8
// baseline (432.654 us; speedup 1.0000x reference)
//
#include <hip/hip_runtime.h>
#include <math.h>

#define OBS 114
#define ROWS_PER_BLOCK 8    // one wave per block, 4x2 rows
#define BSTRIDE 104         // fp32 buffer row stride (100 + pad)

typedef float v2f __attribute__((ext_vector_type(2)));
__device__ __forceinline__ v2f v2fma(v2f a, v2f b, v2f c) { return __builtin_elementwise_fma(a, b, c); }
__device__ __forceinline__ v2f vsplat(float x) { v2f r; r.x = x; r.y = x; return r; }

__device__ __forceinline__ float fast_tanh(float x) {
    float e = __expf(2.0f * x);
    return 1.0f - 2.0f * __builtin_amdgcn_rcpf(e + 1.0f);
}

template<int CTRL>
__device__ __forceinline__ float dpp_add(float x) {
    int y = __builtin_amdgcn_update_dpp(0, __float_as_int(x), CTRL, 0xF, 0xF, true);
    return x + __int_as_float(y);
}
// sum across each 16-lane row (serves 4 rows per wave simultaneously)
__device__ __forceinline__ float row16_sum(float x) {
    x = dpp_add<0xB1>(x);    // quad_perm xor1
    x = dpp_add<0x4E>(x);    // quad_perm xor2
    x = dpp_add<0x124>(x);   // row_ror:4
    x = dpp_add<0x128>(x);   // row_ror:8
    return x;
}
__device__ __forceinline__ float f4c(const float4& v, int j) {
    return j==0?v.x: j==1?v.y: j==2?v.z: v.w;
}

// ---- repack [K x 100] row-major weights into [K][16 j][8 i] so each lane's
// 7 h-slots (h = j+16i) are 2 contiguous float4 loads; masked slots -> 0 ----
__global__ __launch_bounds__(256) void repack_kernel(
    const float* __restrict__ Ac, const float* __restrict__ Lc,
    const float* __restrict__ fcW, const float* __restrict__ f1W,
    const float* __restrict__ f2W, float* __restrict__ ws)
{
    int tid = blockIdx.x*256 + threadIdx.x;   // 800 krows * 128
    if (tid >= 800*128) return;
    int krow = tid >> 7;
    int idx  = tid & 127;
    int j = idx >> 3, i = idx & 7;
    int h = j + 16*i;
    const float* src; int k;
    if (krow < 100)      { src = Ac;  k = krow; }
    else if (krow < 200) { src = Lc;  k = krow-100; }
    else if (krow < 300) { src = fcW; k = krow-200; }
    else if (krow < 700) { src = f1W; k = krow-300; }
    else                 { src = f2W; k = krow-700; }
    float v = (i < 7 && h < 100) ? src[k*100 + h] : 0.f;
    ws[tid] = v;
}

// acc2[p][b] (+)= sum_k sbuf[R_b][k] * Wp[k][j][2p..2p+1]   (packed pk_fma)
template<int NK4>
__device__ __forceinline__ void mm16p(const float* __restrict__ Wp,
    const float (*sbuf)[BSTRIDE], int R0, int R1, int j, v2f acc2[4][2])
{
    const float* wp = Wp + j*8;
#pragma unroll 2
    for (int k4 = 0; k4 < NK4; ++k4) {
        float4 xa = *(const float4*)&sbuf[R0][k4*4];
        float4 xb = *(const float4*)&sbuf[R1][k4*4];
#pragma unroll
        for (int jj=0;jj<4;++jj) {
            const float* w8 = wp + (size_t)(k4*4+jj)*128;
            float4 wlo = *(const float4*)w8;
            float4 whi = *(const float4*)(w8+4);
            v2f w2[4] = {{wlo.x,wlo.y},{wlo.z,wlo.w},{whi.x,whi.y},{whi.z,whi.w}};
            v2f xs0 = vsplat(f4c(xa,jj));
            v2f xs1 = vsplat(f4c(xb,jj));
#pragma unroll
            for (int p=0;p<4;++p) {
                acc2[p][0] = v2fma(xs0, w2[p], acc2[p][0]);
                acc2[p][1] = v2fma(xs1, w2[p], acc2[p][1]);
            }
        }
    }
}

// fused triple matmul sharing the x broadcast (Ac, Lc, fcW)
template<int NK4>
__device__ __forceinline__ void mm16x3(const float* __restrict__ W1,
    const float* __restrict__ W2, const float* __restrict__ W3,
    const float (*sbuf)[BSTRIDE], int R0, int R1, int j,
    v2f a1[4][2], v2f a2[4][2], v2f a3[4][2])
{
    const float* p1 = W1 + j*8;
    const float* p2 = W2 + j*8;
    const float* p3 = W3 + j*8;
#pragma unroll 2
    for (int k4 = 0; k4 < NK4; ++k4) {
        float4 xa = *(const float4*)&sbuf[R0][k4*4];
        float4 xb = *(const float4*)&sbuf[R1][k4*4];
#pragma unroll
        for (int jj=0;jj<4;++jj) {
            size_t off = (size_t)(k4*4+jj)*128;
            float4 u1 = *(const float4*)(p1+off), v1 = *(const float4*)(p1+off+4);
            float4 u2 = *(const float4*)(p2+off), v2 = *(const float4*)(p2+off+4);
            float4 u3 = *(const float4*)(p3+off), v3 = *(const float4*)(p3+off+4);
            v2f w1p[4] = {{u1.x,u1.y},{u1.z,u1.w},{v1.x,v1.y},{v1.z,v1.w}};
            v2f w2p[4] = {{u2.x,u2.y},{u2.z,u2.w},{v2.x,v2.y},{v2.z,v2.w}};
            v2f w3p[4] = {{u3.x,u3.y},{u3.z,u3.w},{v3.x,v3.y},{v3.z,v3.w}};
            v2f xs0 = vsplat(f4c(xa,jj));
            v2f xs1 = vsplat(f4c(xb,jj));
#pragma unroll
            for (int p=0;p<4;++p) {
                a1[p][0]=v2fma(xs0,w1p[p],a1[p][0]); a1[p][1]=v2fma(xs1,w1p[p],a1[p][1]);
                a2[p][0]=v2fma(xs0,w2p[p],a2[p][0]); a2[p][1]=v2fma(xs1,w2p[p],a2[p][1]);
                a3[p][0]=v2fma(xs0,w3p[p],a3[p][0]); a3[p][1]=v2fma(xs1,w3p[p],a3[p][1]);
            }
        }
    }
}

// attention stream, 16-lane layout, batch-interleaved, pk-packed over slot pairs.
// Pre-masked params: masked slots have w=bias=g=0 -> t=tanh(0)=0 contributes nothing.
template<int K, int NA>
__device__ __forceinline__ void attn16(
    const float* __restrict__ W, const float* __restrict__ bb,
    const float* __restrict__ gp, const float* __restrict__ bep,
    const float* __restrict__ in, int xoff,
    float (*sbuf)[BSTRIDE],
    int rowAc, int rowBc, int RA, int RB,
    const v2f qacc[4][2],
    const int hc[7], const float msk[7])
{
    float g[7], be[7];
#pragma unroll
    for (int i=0;i<7;++i) { g[i] = gp[hc[i]]*msk[i]; be[i] = bep[hc[i]]; }
    v2f w2[K][4], bias2[4], g2[4];
#pragma unroll
    for (int p=0;p<4;++p) {
        int i0 = 2*p, i1 = 2*p+1;
        bias2[p].x = bb[hc[i0]]*msk[i0];
        bias2[p].y = (i1<7) ? bb[hc[i1]]*msk[i1] : 0.f;
        g2[p].x = g[i0];
        g2[p].y = (i1<7) ? g[i1] : 0.f;
#pragma unroll
        for (int k=0;k<K;++k) {
            w2[k][p].x = W[k*100+hc[i0]]*msk[i0];
            w2[k][p].y = (i1<7) ? W[k*100+hc[i1]]*msk[i1] : 0.f;
        }
    }
    v2f qg2[2][4]; float C1[2];
#pragma unroll
    for (int b=0;b<2;++b) {
        v2f c2 = {0.f,0.f};
#pragma unroll
        for (int p=0;p<4;++p) { qg2[b][p] = qacc[p][b]*g2[p]; c2 += qg2[b][p]; }
        C1[b] = row16_sum(c2.x + c2.y);
    }
    const float* xr0 = in + (size_t)rowAc*OBS + xoff;
    const float* xr1 = in + (size_t)rowBc*OBS + xoff;
    float s[2] = {0.f,0.f}, bacc[2] = {0.f,0.f};
    v2f A2[2][4];
#pragma unroll
    for (int b=0;b<2;++b)
#pragma unroll
        for (int p=0;p<4;++p) A2[b][p] = (v2f){0.f,0.f};

#pragma unroll 1
    for (int n=0;n<NA;++n) {
        float x[2][K];
#pragma unroll
        for (int k=0;k<K;++k) { x[0][k] = xr0[n*K+k]; x[1][k] = xr1[n*K+k]; }
        v2f t2[2][4];
        float sa[2], sq[2], sd[2];
#pragma unroll
        for (int b=0;b<2;++b) {
            v2f a2[4];
#pragma unroll
            for (int p=0;p<4;++p) a2[p] = bias2[p];
#pragma unroll
            for (int k=0;k<K;++k) {
                v2f xs = vsplat(x[b][k]);
#pragma unroll
                for (int p=0;p<4;++p) a2[p] = v2fma(xs, w2[k][p], a2[p]);
            }
            t2[b][0].x = fast_tanh(a2[0].x); t2[b][0].y = fast_tanh(a2[0].y);
            t2[b][1].x = fast_tanh(a2[1].x); t2[b][1].y = fast_tanh(a2[1].y);
            t2[b][2].x = fast_tanh(a2[2].x); t2[b][2].y = fast_tanh(a2[2].y);
            t2[b][3].x = fast_tanh(a2[3].x); t2[b][3].y = 0.f;
            v2f sa2 = {0.f,0.f}, sq2 = {0.f,0.f}, sd2 = {0.f,0.f};
#pragma unroll
            for (int p=0;p<4;++p) {
                sa2 += t2[b][p];
                sq2 = v2fma(t2[b][p], t2[b][p], sq2);
                sd2 = v2fma(qg2[b][p], t2[b][p], sd2);
            }
            sa[b] = sa2.x + sa2.y;
            sq[b] = sq2.x + sq2.y;
            sd[b] = sd2.x + sd2.y;
        }
#pragma unroll
        for (int b=0;b<2;++b) { sa[b]=row16_sum(sa[b]); sq[b]=row16_sum(sq[b]); sd[b]=row16_sum(sd[b]); }
#pragma unroll
        for (int b=0;b<2;++b) {
            float mean = sa[b]*0.01f;
            float var  = fmaf(sq[b],0.01f,-mean*mean);
            float rinv = __builtin_amdgcn_rsqf(var + 1e-5f);
            float logit = (sd[b]-mean*C1[b])*rinv;   // q.be term agent-constant -> dropped
            float wgt = __expf(fminf(logit,80.f));
            s[b] += wgt;
            float wr = wgt*rinv;
            bacc[b] = fmaf(wr,mean,bacc[b]);
            v2f wrs = vsplat(wr);
#pragma unroll
            for (int p=0;p<4;++p) A2[b][p] = v2fma(wrs, t2[b][p], A2[b][p]);
        }
    }
#pragma unroll
    for (int b=0;b<2;++b) {
        int R = b ? RB : RA;
        float inv = __builtin_amdgcn_rcpf(s[b]);
#pragma unroll
        for (int i=0;i<7;++i) {
            float Ai = (i&1) ? A2[b][i>>1].y : A2[b][i>>1].x;
            if (msk[i]>0.f) sbuf[R][hc[i]] = fmaf(g[i], (Ai-bacc[b])*inv, be[i]);
        }
    }
}

// LN(tanh(acc+bias)) for both batches from packed acc; masked slots contribute 0.
__device__ __forceinline__ void ln_pairp(const v2f acc2[4][2],
    const float* __restrict__ bp, const float* __restrict__ gp, const float* __restrict__ bep,
    const int hc[7], const float msk[7], float outv[2][7])
{
    float bias[7], g[7], be[7];
#pragma unroll
    for (int i=0;i<7;++i) { bias[i]=bp[hc[i]]*msk[i]; g[i]=gp[hc[i]]; be[i]=bep[hc[i]]; }
    float t[2][7], sa[2], sq[2];
#pragma unroll
    for (int b=0;b<2;++b) { sa[b]=0.f; sq[b]=0.f; }
#pragma unroll
    for (int i=0;i<7;++i) {
#pragma unroll
        for (int b=0;b<2;++b) {
            float a = (i&1) ? acc2[i>>1][b].y : acc2[i>>1][b].x;
            float tt = fast_tanh(a + bias[i]);
            t[b][i] = tt; sa[b] += tt*msk[i]; sq[b] = fmaf(tt*msk[i],tt,sq[b]);
        }
    }
#pragma unroll
    for (int b=0;b<2;++b) { sa[b]=row16_sum(sa[b]); sq[b]=row16_sum(sq[b]); }
#pragma unroll
    for (int b=0;b<2;++b) {
        float mean = sa[b]*0.01f;
        float var  = fmaf(sq[b],0.01f,-mean*mean);
        float rinv = __builtin_amdgcn_rsqf(var + 1e-5f);
#pragma unroll
        for (int i=0;i<7;++i) outv[b][i] = fmaf((t[b][i]-mean)*rinv, g[i], be[i]);
    }
}

__global__ __launch_bounds__(64, 4)
void obs_encoder_kernel(const float* __restrict__ in,
    const float* __restrict__ sW, const float* __restrict__ sb, const float* __restrict__ sg, const float* __restrict__ sbe,
    const float* __restrict__ oW, const float* __restrict__ ob, const float* __restrict__ og, const float* __restrict__ obe,
    const float* __restrict__ lW, const float* __restrict__ lb, const float* __restrict__ lg, const float* __restrict__ lbe,
    const float* __restrict__ gW, const float* __restrict__ gb, const float* __restrict__ gg_, const float* __restrict__ gbe,
    const float* __restrict__ fcb, const float* __restrict__ fcg, const float* __restrict__ fcbe,
    const float* __restrict__ f1b, const float* __restrict__ f1g, const float* __restrict__ f1be,
    const float* __restrict__ f2b, const float* __restrict__ f2g, const float* __restrict__ f2be,
    const float* __restrict__ wsf,
    float* __restrict__ out, int B)
{
    const int lane = threadIdx.x;
    const int j    = lane & 15;
    const int rw   = lane >> 4;
    const int rowBase = blockIdx.x*ROWS_PER_BLOCK;
    const int rowA = rowBase + rw;        // batch 0
    const int rowB = rowBase + 4 + rw;    // batch 1
    const int RA = rw, RB = 4 + rw;
    const int rowAc = min(rowA, B-1), rowBc = min(rowB, B-1);

    int hc[7]; float msk[7];
#pragma unroll
    for (int i=0;i<7;++i) {
        int h = j + 16*i;
        bool v = h < 100;
        hc[i] = v ? h : 99;
        msk[i] = v ? 1.f : 0.f;
    }

    // Single reusable fp32 segment buffer: emb -> gi -> va -> vl -> vg -> h1.
    // f1 accumulated incrementally; 8*104*4 = 3.3 KB LDS. One wave per block.
    __shared__ __align__(16) float sbuf[ROWS_PER_BLOCK][BSTRIDE];

    const float* Acp = wsf;
    const float* Lcp = wsf + 12800;
    const float* fcp = wsf + 25600;
    const float* f1p = wsf + 38400;
    const float* f2p = wsf + 89600;

    // ---- self encoder -> sbuf ----
    {
        float w[4][7], bias[7], g[7], be[7];
#pragma unroll
        for (int i=0;i<7;++i) {
#pragma unroll
            for (int k=0;k<4;++k) w[k][i] = sW[k*100 + hc[i]] * msk[i];
            bias[i] = sb[hc[i]] * msk[i]; g[i] = sg[hc[i]]; be[i] = sbe[hc[i]];
        }
        const float* xr0 = in + (size_t)rowAc*OBS;
        const float* xr1 = in + (size_t)rowBc*OBS;
        float x[2][4];
#pragma unroll
        for (int k=0;k<4;++k) { x[0][k]=xr0[k]; x[1][k]=xr1[k]; }
        float t[2][7], sa[2], sq[2];
#pragma unroll
        for (int b=0;b<2;++b) { sa[b]=0.f; sq[b]=0.f; }
#pragma unroll
        for (int i=0;i<7;++i) {
#pragma unroll
            for (int b=0;b<2;++b) {
                float a = bias[i];
#pragma unroll
                for (int k=0;k<4;++k) a = fmaf(x[b][k], w[k][i], a);
                float tt = fast_tanh(a);
                t[b][i] = tt; sa[b] += tt*msk[i]; sq[b] = fmaf(tt*msk[i],tt,sq[b]);
            }
        }
#pragma unroll
        for (int b=0;b<2;++b) { sa[b]=row16_sum(sa[b]); sq[b]=row16_sum(sq[b]); }
#pragma unroll
        for (int b=0;b<2;++b) {
            int R = b ? RB : RA;
            float mean = sa[b]*0.01f;
            float var  = fmaf(sq[b],0.01f,-mean*mean);
            float rinv = __builtin_amdgcn_rsqf(var + 1e-5f);
#pragma unroll
            for (int i=0;i<7;++i)
                if (msk[i] > 0.f) sbuf[R][hc[i]] = fmaf((t[b][i]-mean)*rinv, g[i], be[i]);
        }
    }

    // ---- qa/ql/tg = emb @ {Ac, Lc, fcW} fused (emb still in sbuf) ----
    v2f accA[4][2], accL[4][2], accF[4][2], f1a[4][2];
#pragma unroll
    for (int p=0;p<4;++p)
#pragma unroll
        for (int b=0;b<2;++b) {
            accA[p][b] = (v2f){0.f,0.f}; accL[p][b] = (v2f){0.f,0.f};
            accF[p][b] = (v2f){0.f,0.f}; f1a[p][b]  = (v2f){0.f,0.f};
        }
    mm16x3<25>(Acp, Lcp, fcp, sbuf, RA, RB, j, accA, accL, accF);

    // ---- gi = LN(tanh(tg + fcb)) -> sbuf (overwrites emb), f1 partial k 0..99 ----
    {
        float outv[2][7];
        ln_pairp(accF, fcb, fcg, fcbe, hc, msk, outv);
#pragma unroll
        for (int b=0;b<2;++b) {
            int R = b ? RB : RA;
#pragma unroll
            for (int i=0;i<7;++i)
                if (msk[i] > 0.f) sbuf[R][hc[i]] = outv[b][i];
        }
    }
    mm16p<25>(f1p, sbuf, RA, RB, j, f1a);

    // ---- attention streams interleaved with f1 partials (ql reused for goal per ref bug) ----
    attn16<2,15>(oW, ob, og,  obe, in, 52, sbuf, rowAc, rowBc, RA, RB, accA, hc, msk);
    mm16p<25>(f1p + 100*128, sbuf, RA, RB, j, f1a);
    attn16<3,16>(lW, lb, lg,  lbe, in, 4,  sbuf, rowAc, rowBc, RA, RB, accL, hc, msk);
    mm16p<25>(f1p + 200*128, sbuf, RA, RB, j, f1a);
    attn16<2,16>(gW, gb, gg_, gbe, in, 82, sbuf, rowAc, rowBc, RA, RB, accL, hc, msk);
    mm16p<25>(f1p + 300*128, sbuf, RA, RB, j, f1a);

    // ---- h1 = LN(tanh(f1a + f1b)) -> sbuf ----
    {
        float outv[2][7];
        ln_pairp(f1a, f1b, f1g, f1be, hc, msk, outv);
#pragma unroll
        for (int b=0;b<2;++b) {
            int R = b ? RB : RA;
#pragma unroll
            for (int i=0;i<7;++i)
                if (msk[i] > 0.f) sbuf[R][hc[i]] = outv[b][i];
        }
    }

    // ---- f2: [100] -> [100], LN -> out ----
    {
        v2f accO[4][2];
#pragma unroll
        for (int p=0;p<4;++p) { accO[p][0]=(v2f){0.f,0.f}; accO[p][1]=(v2f){0.f,0.f}; }
        mm16p<25>(f2p, sbuf, RA, RB, j, accO);
        float outv[2][7];
        ln_pairp(accO, f2b, f2g, f2be, hc, msk, outv);
#pragma unroll
        for (int b=0;b<2;++b) {
            int row = b ? rowB : rowA;
            if (row < B) {
#pragma unroll
                for (int i=0;i<7;++i)
                    if (msk[i] > 0.f)
                        out[(size_t)row*100 + hc[i]] = outv[b][i];
            }
        }
    }
}

extern "C" void kernel_launch(void* const* d_in, const int* in_sizes, int n_in,
                              void* d_out, int out_size, void* d_ws, size_t ws_size,
                              hipStream_t stream) {
    const float* in  = (const float*)d_in[0];
    const float* sW  = (const float*)d_in[2];
    const float* sb  = (const float*)d_in[3];
    const float* sg  = (const float*)d_in[4];
    const float* sbe = (const float*)d_in[5];
    const float* oW  = (const float*)d_in[6];
    const float* ob  = (const float*)d_in[7];
    const float* og  = (const float*)d_in[8];
    const float* obe = (const float*)d_in[9];
    const float* lW  = (const float*)d_in[10];
    const float* lb  = (const float*)d_in[11];
    const float* lg  = (const float*)d_in[12];
    const float* lbe = (const float*)d_in[13];
    const float* gW  = (const float*)d_in[14];
    const float* gb  = (const float*)d_in[15];
    const float* gg  = (const float*)d_in[16];
    const float* gbe = (const float*)d_in[17];
    const float* Ac  = (const float*)d_in[18];
    const float* Lc  = (const float*)d_in[19];
    const float* fcW = (const float*)d_in[20];
    const float* fcb = (const float*)d_in[21];
    const float* fcg = (const float*)d_in[22];
    const float* fcbe= (const float*)d_in[23];
    const float* f1W = (const float*)d_in[24];
    const float* f1b = (const float*)d_in[25];
    const float* f1g = (const float*)d_in[26];
    const float* f1be= (const float*)d_in[27];
    const float* f2W = (const float*)d_in[28];
    const float* f2b = (const float*)d_in[29];
    const float* f2g = (const float*)d_in[30];
    const float* f2be= (const float*)d_in[31];
    float* out = (float*)d_out;
    float* wsf = (float*)d_ws;

    int B = in_sizes[0] / OBS;
    repack_kernel<<<(800*128 + 255)/256, 256, 0, stream>>>(Ac, Lc, fcW, f1W, f2W, wsf);
    int blocks = (B + ROWS_PER_BLOCK - 1) / ROWS_PER_BLOCK;
    obs_encoder_kernel<<<blocks, 64, 0, stream>>>(in,
        sW, sb, sg, sbe, oW, ob, og, obe, lW, lb, lg, lbe, gW, gb, gg, gbe,
        fcb, fcg, fcbe, f1b, f1g, f1be, f2b, f2g, f2be,
        wsf, out, B);
}

// Round 9
// 371.663 us; speedup vs baseline: 1.1641x; 1.1641x over previous
//
#include <hip/hip_runtime.h>
#include <math.h>

#define OBS 114
#define ROWS_PER_BLOCK 16   // 2 waves x 8 rows
#define BSTRIDE 104         // fp32 buffer row stride (100 + pad)

typedef float v2f __attribute__((ext_vector_type(2)));
__device__ __forceinline__ v2f v2fma(v2f a, v2f b, v2f c) { return __builtin_elementwise_fma(a, b, c); }
__device__ __forceinline__ v2f vsplat(float x) { v2f r; r.x = x; r.y = x; return r; }

__device__ __forceinline__ float fast_tanh(float x) {
    float e = __expf(2.0f * x);
    return 1.0f - 2.0f * __builtin_amdgcn_rcpf(e + 1.0f);
}

template<int CTRL>
__device__ __forceinline__ float dpp_add(float x) {
    int y = __builtin_amdgcn_update_dpp(0, __float_as_int(x), CTRL, 0xF, 0xF, true);
    return x + __int_as_float(y);
}
// sum across each 16-lane row (serves 4 rows per wave simultaneously)
__device__ __forceinline__ float row16_sum(float x) {
    x = dpp_add<0xB1>(x);    // quad_perm xor1
    x = dpp_add<0x4E>(x);    // quad_perm xor2
    x = dpp_add<0x124>(x);   // row_ror:4
    x = dpp_add<0x128>(x);   // row_ror:8
    return x;
}
__device__ __forceinline__ float f4c(const float4& v, int j) {
    return j==0?v.x: j==1?v.y: j==2?v.z: v.w;
}

// ---- repack [K x 100] row-major weights into [K][16 j][8 i] so each lane's
// 7 h-slots (h = j+16i) are 2 contiguous float4 loads; masked slots -> 0 ----
__global__ __launch_bounds__(256) void repack_kernel(
    const float* __restrict__ Ac, const float* __restrict__ Lc,
    const float* __restrict__ fcW, const float* __restrict__ f1W,
    const float* __restrict__ f2W, float* __restrict__ ws)
{
    int tid = blockIdx.x*256 + threadIdx.x;   // 800 krows * 128
    if (tid >= 800*128) return;
    int krow = tid >> 7;
    int idx  = tid & 127;
    int j = idx >> 3, i = idx & 7;
    int h = j + 16*i;
    const float* src; int k;
    if (krow < 100)      { src = Ac;  k = krow; }
    else if (krow < 200) { src = Lc;  k = krow-100; }
    else if (krow < 300) { src = fcW; k = krow-200; }
    else if (krow < 700) { src = f1W; k = krow-300; }
    else                 { src = f2W; k = krow-700; }
    float v = (i < 7 && h < 100) ? src[k*100 + h] : 0.f;
    ws[tid] = v;
}

// acc2[p][b] += sum_k sbuf[R_b][k] * Wp[k][j][2p..2p+1]  (v_pk_fma_f32; accumulating)
template<int NK4>
__device__ __forceinline__ void mm16p(const float* __restrict__ Wp,
    const float (*sbuf)[BSTRIDE], int R0, int R1, int j, v2f acc2[4][2])
{
    const float* wp = Wp + j*8;
#pragma unroll 2
    for (int k4 = 0; k4 < NK4; ++k4) {
        float4 xa = *(const float4*)&sbuf[R0][k4*4];
        float4 xb = *(const float4*)&sbuf[R1][k4*4];
#pragma unroll
        for (int jj=0;jj<4;++jj) {
            const float* w8 = wp + (size_t)(k4*4+jj)*128;
            float4 wlo = *(const float4*)w8;
            float4 whi = *(const float4*)(w8+4);
            v2f w2[4] = {{wlo.x,wlo.y},{wlo.z,wlo.w},{whi.x,whi.y},{whi.z,whi.w}};
            v2f xs0 = vsplat(f4c(xa,jj));
            v2f xs1 = vsplat(f4c(xb,jj));
#pragma unroll
            for (int p=0;p<4;++p) {
                acc2[p][0] = v2fma(xs0, w2[p], acc2[p][0]);
                acc2[p][1] = v2fma(xs1, w2[p], acc2[p][1]);
            }
        }
    }
}

// attention stream, 16-lane layout, batch-interleaved (2 independent chains).
// Pre-masked params: masked slots have w=bias=g=0 -> t=tanh(0)=0 contributes nothing.
// Writes result segment into sbuf[R][h].  (round-7 scalar version, register-lean)
template<int K, int NA>
__device__ __forceinline__ void attn16(
    const float* __restrict__ W, const float* __restrict__ bb,
    const float* __restrict__ gp, const float* __restrict__ bep,
    const float* __restrict__ in, int xoff,
    float (*sbuf)[BSTRIDE],
    int rowAc, int rowBc, int RA, int RB,
    const float qacc[7][2],
    const int hc[7], const float msk[7])
{
    float w[K][7], bias[7], g[7], be[7];
#pragma unroll
    for (int i=0;i<7;++i) {
#pragma unroll
        for (int k=0;k<K;++k) w[k][i] = W[k*100 + hc[i]] * msk[i];
        bias[i] = bb[hc[i]] * msk[i];
        g[i]    = gp[hc[i]] * msk[i];
        be[i]   = bep[hc[i]];
    }
    float qg[2][7], C1[2];
#pragma unroll
    for (int b=0;b<2;++b) {
        float c = 0.f;
#pragma unroll
        for (int i=0;i<7;++i) { qg[b][i] = qacc[i][b]*g[i]; c += qg[b][i]; }
        C1[b] = row16_sum(c);
    }
    const float* xr0 = in + (size_t)rowAc*OBS + xoff;
    const float* xr1 = in + (size_t)rowBc*OBS + xoff;
    float s[2] = {0.f,0.f}, bacc[2] = {0.f,0.f};
    float A[2][7];
#pragma unroll
    for (int b=0;b<2;++b)
#pragma unroll
        for (int i=0;i<7;++i) A[b][i]=0.f;

#pragma unroll 1
    for (int n=0;n<NA;++n) {
        float x0[K], x1[K];
#pragma unroll
        for (int k=0;k<K;++k) { x0[k] = xr0[n*K+k]; x1[k] = xr1[n*K+k]; }
        float t[2][7], sa[2], sq[2], sd[2];
#pragma unroll
        for (int b=0;b<2;++b) { sa[b]=0.f; sq[b]=0.f; sd[b]=0.f; }
#pragma unroll
        for (int i=0;i<7;++i) {
#pragma unroll
            for (int b=0;b<2;++b) {
                float a = bias[i];
#pragma unroll
                for (int k=0;k<K;++k) a = fmaf(b ? x1[k] : x0[k], w[k][i], a);
                float tt = fast_tanh(a);
                t[b][i] = tt;
                sa[b] += tt;
                sq[b] = fmaf(tt,tt,sq[b]);
                sd[b] = fmaf(qg[b][i],tt,sd[b]);
            }
        }
#pragma unroll
        for (int b=0;b<2;++b) { sa[b]=row16_sum(sa[b]); sq[b]=row16_sum(sq[b]); sd[b]=row16_sum(sd[b]); }
#pragma unroll
        for (int b=0;b<2;++b) {
            float mean = sa[b]*0.01f;
            float var  = fmaf(sq[b],0.01f,-mean*mean);
            float rinv = __builtin_amdgcn_rsqf(var + 1e-5f);
            float logit = (sd[b]-mean*C1[b])*rinv;   // q.be term agent-constant -> dropped
            float wgt = __expf(fminf(logit,80.f));
            s[b] += wgt;
            float wr = wgt*rinv;
            bacc[b] = fmaf(wr,mean,bacc[b]);
#pragma unroll
            for (int i=0;i<7;++i) A[b][i] = fmaf(wr,t[b][i],A[b][i]);
        }
    }
#pragma unroll
    for (int b=0;b<2;++b) {
        int R = b ? RB : RA;
        float inv = __builtin_amdgcn_rcpf(s[b]);
#pragma unroll
        for (int i=0;i<7;++i)
            if (msk[i]>0.f) sbuf[R][hc[i]] = fmaf(g[i], (A[b][i]-bacc[b])*inv, be[i]);
    }
}

// LN(tanh(acc+bias)) for both batches from packed acc; masked slots contribute 0.
__device__ __forceinline__ void ln_pairp(const v2f acc2[4][2],
    const float* __restrict__ bp, const float* __restrict__ gp, const float* __restrict__ bep,
    const int hc[7], const float msk[7], float outv[2][7])
{
    float bias[7], g[7], be[7];
#pragma unroll
    for (int i=0;i<7;++i) { bias[i]=bp[hc[i]]*msk[i]; g[i]=gp[hc[i]]; be[i]=bep[hc[i]]; }
    float t[2][7], sa[2], sq[2];
#pragma unroll
    for (int b=0;b<2;++b) { sa[b]=0.f; sq[b]=0.f; }
#pragma unroll
    for (int i=0;i<7;++i) {
#pragma unroll
        for (int b=0;b<2;++b) {
            float a = (i&1) ? acc2[i>>1][b].y : acc2[i>>1][b].x;
            float tt = fast_tanh(a + bias[i]);
            t[b][i] = tt; sa[b] += tt*msk[i]; sq[b] = fmaf(tt*msk[i],tt,sq[b]);
        }
    }
#pragma unroll
    for (int b=0;b<2;++b) { sa[b]=row16_sum(sa[b]); sq[b]=row16_sum(sq[b]); }
#pragma unroll
    for (int b=0;b<2;++b) {
        float mean = sa[b]*0.01f;
        float var  = fmaf(sq[b],0.01f,-mean*mean);
        float rinv = __builtin_amdgcn_rsqf(var + 1e-5f);
#pragma unroll
        for (int i=0;i<7;++i) outv[b][i] = fmaf((t[b][i]-mean)*rinv, g[i], be[i]);
    }
}

__global__ __launch_bounds__(128, 4)
void obs_encoder_kernel(const float* __restrict__ in,
    const float* __restrict__ sW, const float* __restrict__ sb, const float* __restrict__ sg, const float* __restrict__ sbe,
    const float* __restrict__ oW, const float* __restrict__ ob, const float* __restrict__ og, const float* __restrict__ obe,
    const float* __restrict__ lW, const float* __restrict__ lb, const float* __restrict__ lg, const float* __restrict__ lbe,
    const float* __restrict__ gW, const float* __restrict__ gb, const float* __restrict__ gg_, const float* __restrict__ gbe,
    const float* __restrict__ fcb, const float* __restrict__ fcg, const float* __restrict__ fcbe,
    const float* __restrict__ f1b, const float* __restrict__ f1g, const float* __restrict__ f1be,
    const float* __restrict__ f2b, const float* __restrict__ f2g, const float* __restrict__ f2be,
    const float* __restrict__ wsf,
    float* __restrict__ out, int B)
{
    const int lane = threadIdx.x & 63;
    const int wv   = threadIdx.x >> 6;
    const int j    = lane & 15;
    const int rw   = lane >> 4;
    const int rowBase = blockIdx.x*ROWS_PER_BLOCK + wv*8;
    const int rowA = rowBase + rw;        // batch 0
    const int rowB = rowBase + 4 + rw;    // batch 1
    const int RA = wv*8 + rw, RB = RA + 4;
    const int rowAc = min(rowA, B-1), rowBc = min(rowB, B-1);

    int hc[7]; float msk[7];
#pragma unroll
    for (int i=0;i<7;++i) {
        int h = j + 16*i;
        bool v = h < 100;
        hc[i] = v ? h : 99;
        msk[i] = v ? 1.f : 0.f;
    }

    // Single reusable fp32 segment buffer: emb -> gi -> va -> vl -> vg -> h1.
    // f1 accumulated incrementally (f1W split into 4 k-blocks): LDS = 6.6 KB.
    // Waves touch disjoint rows -> no barriers.
    __shared__ __align__(16) float sbuf[ROWS_PER_BLOCK][BSTRIDE];

    const float* Acp = wsf;
    const float* Lcp = wsf + 12800;
    const float* fcp = wsf + 25600;
    const float* f1p = wsf + 38400;
    const float* f2p = wsf + 89600;

    // ---- self encoder -> sbuf ----
    {
        float w[4][7], bias[7], g[7], be[7];
#pragma unroll
        for (int i=0;i<7;++i) {
#pragma unroll
            for (int k=0;k<4;++k) w[k][i] = sW[k*100 + hc[i]] * msk[i];
            bias[i] = sb[hc[i]] * msk[i]; g[i] = sg[hc[i]]; be[i] = sbe[hc[i]];
        }
        const float* xr0 = in + (size_t)rowAc*OBS;
        const float* xr1 = in + (size_t)rowBc*OBS;
        float x[2][4];
#pragma unroll
        for (int k=0;k<4;++k) { x[0][k]=xr0[k]; x[1][k]=xr1[k]; }
        float t[2][7], sa[2], sq[2];
#pragma unroll
        for (int b=0;b<2;++b) { sa[b]=0.f; sq[b]=0.f; }
#pragma unroll
        for (int i=0;i<7;++i) {
#pragma unroll
            for (int b=0;b<2;++b) {
                float a = bias[i];
#pragma unroll
                for (int k=0;k<4;++k) a = fmaf(x[b][k], w[k][i], a);
                float tt = fast_tanh(a);
                t[b][i] = tt; sa[b] += tt*msk[i]; sq[b] = fmaf(tt*msk[i],tt,sq[b]);
            }
        }
#pragma unroll
        for (int b=0;b<2;++b) { sa[b]=row16_sum(sa[b]); sq[b]=row16_sum(sq[b]); }
#pragma unroll
        for (int b=0;b<2;++b) {
            int R = b ? RB : RA;
            float mean = sa[b]*0.01f;
            float var  = fmaf(sq[b],0.01f,-mean*mean);
            float rinv = __builtin_amdgcn_rsqf(var + 1e-5f);
#pragma unroll
            for (int i=0;i<7;++i)
                if (msk[i] > 0.f) sbuf[R][hc[i]] = fmaf((t[b][i]-mean)*rinv, g[i], be[i]);
        }
    }

    // ---- qa = emb@Ac, ql = emb@Lc, tg = emb@fcW (separate passes; emb in sbuf) ----
    v2f accA[4][2], accL[4][2], accF[4][2], f1a[4][2];
#pragma unroll
    for (int p=0;p<4;++p)
#pragma unroll
        for (int b=0;b<2;++b) {
            accA[p][b] = (v2f){0.f,0.f}; accL[p][b] = (v2f){0.f,0.f};
            accF[p][b] = (v2f){0.f,0.f}; f1a[p][b]  = (v2f){0.f,0.f};
        }
    mm16p<25>(Acp, sbuf, RA, RB, j, accA);
    mm16p<25>(Lcp, sbuf, RA, RB, j, accL);
    mm16p<25>(fcp, sbuf, RA, RB, j, accF);

    // unpack q-vectors to scalar for attn (register-lean)
    float qA[7][2], qL[7][2];
#pragma unroll
    for (int i=0;i<7;++i) {
#pragma unroll
        for (int b=0;b<2;++b) {
            qA[i][b] = (i&1) ? accA[i>>1][b].y : accA[i>>1][b].x;
            qL[i][b] = (i&1) ? accL[i>>1][b].y : accL[i>>1][b].x;
        }
    }

    // ---- gi = LN(tanh(tg + fcb)) -> sbuf (overwrites emb), f1 partial k 0..99 ----
    {
        float outv[2][7];
        ln_pairp(accF, fcb, fcg, fcbe, hc, msk, outv);
#pragma unroll
        for (int b=0;b<2;++b) {
            int R = b ? RB : RA;
#pragma unroll
            for (int i=0;i<7;++i)
                if (msk[i] > 0.f) sbuf[R][hc[i]] = outv[b][i];
        }
    }
    mm16p<25>(f1p, sbuf, RA, RB, j, f1a);

    // ---- attention streams interleaved with f1 partials (ql reused for goal per ref bug) ----
    attn16<2,15>(oW, ob, og,  obe, in, 52, sbuf, rowAc, rowBc, RA, RB, qA, hc, msk);
    mm16p<25>(f1p + 100*128, sbuf, RA, RB, j, f1a);
    attn16<3,16>(lW, lb, lg,  lbe, in, 4,  sbuf, rowAc, rowBc, RA, RB, qL, hc, msk);
    mm16p<25>(f1p + 200*128, sbuf, RA, RB, j, f1a);
    attn16<2,16>(gW, gb, gg_, gbe, in, 82, sbuf, rowAc, rowBc, RA, RB, qL, hc, msk);
    mm16p<25>(f1p + 300*128, sbuf, RA, RB, j, f1a);

    // ---- h1 = LN(tanh(f1a + f1b)) -> sbuf ----
    {
        float outv[2][7];
        ln_pairp(f1a, f1b, f1g, f1be, hc, msk, outv);
#pragma unroll
        for (int b=0;b<2;++b) {
            int R = b ? RB : RA;
#pragma unroll
            for (int i=0;i<7;++i)
                if (msk[i] > 0.f) sbuf[R][hc[i]] = outv[b][i];
        }
    }

    // ---- f2: [100] -> [100], LN -> out ----
    {
        v2f accO[4][2];
#pragma unroll
        for (int p=0;p<4;++p) { accO[p][0]=(v2f){0.f,0.f}; accO[p][1]=(v2f){0.f,0.f}; }
        mm16p<25>(f2p, sbuf, RA, RB, j, accO);
        float outv[2][7];
        ln_pairp(accO, f2b, f2g, f2be, hc, msk, outv);
#pragma unroll
        for (int b=0;b<2;++b) {
            int row = b ? rowB : rowA;
            if (row < B) {
#pragma unroll
                for (int i=0;i<7;++i)
                    if (msk[i] > 0.f)
                        out[(size_t)row*100 + hc[i]] = outv[b][i];
            }
        }
    }
}

extern "C" void kernel_launch(void* const* d_in, const int* in_sizes, int n_in,
                              void* d_out, int out_size, void* d_ws, size_t ws_size,
                              hipStream_t stream) {
    const float* in  = (const float*)d_in[0];
    const float* sW  = (const float*)d_in[2];
    const float* sb  = (const float*)d_in[3];
    const float* sg  = (const float*)d_in[4];
    const float* sbe = (const float*)d_in[5];
    const float* oW  = (const float*)d_in[6];
    const float* ob  = (const float*)d_in[7];
    const float* og  = (const float*)d_in[8];
    const float* obe = (const float*)d_in[9];
    const float* lW  = (const float*)d_in[10];
    const float* lb  = (const float*)d_in[11];
    const float* lg  = (const float*)d_in[12];
    const float* lbe = (const float*)d_in[13];
    const float* gW  = (const float*)d_in[14];
    const float* gb  = (const float*)d_in[15];
    const float* gg  = (const float*)d_in[16];
    const float* gbe = (const float*)d_in[17];
    const float* Ac  = (const float*)d_in[18];
    const float* Lc  = (const float*)d_in[19];
    const float* fcW = (const float*)d_in[20];
    const float* fcb = (const float*)d_in[21];
    const float* fcg = (const float*)d_in[22];
    const float* fcbe= (const float*)d_in[23];
    const float* f1W = (const float*)d_in[24];
    const float* f1b = (const float*)d_in[25];
    const float* f1g = (const float*)d_in[26];
    const float* f1be= (const float*)d_in[27];
    const float* f2W = (const float*)d_in[28];
    const float* f2b = (const float*)d_in[29];
    const float* f2g = (const float*)d_in[30];
    const float* f2be= (const float*)d_in[31];
    float* out = (float*)d_out;
    float* wsf = (float*)d_ws;

    int B = in_sizes[0] / OBS;
    repack_kernel<<<(800*128 + 255)/256, 256, 0, stream>>>(Ac, Lc, fcW, f1W, f2W, wsf);
    int blocks = (B + ROWS_PER_BLOCK - 1) / ROWS_PER_BLOCK;
    obs_encoder_kernel<<<blocks, 128, 0, stream>>>(in,
        sW, sb, sg, sbe, oW, ob, og, obe, lW, lb, lg, lbe, gW, gb, gg, gbe,
        fcb, fcg, fcbe, f1b, f1g, f1be, f2b, f2g, f2be,
        wsf, out, B);
}